// Round 2
// baseline (3598.431 us; speedup 1.0000x reference)
//
#include <hip/hip_runtime.h>
#include <math.h>

// ---------------- constants ----------------
#define T_STEPS 50
#define NB 512          // S*B batch rows
#define ELEMS 3072      // 128*24
#define RS2 0.70710678118654752f
#define INV_SQRT_L 0.40824829046386302f

struct SchedArg { float cx0[T_STEPS], cxt[T_STEPS], sig[T_STEPS], s1m[T_STEPS], isab[T_STEPS]; };
struct FreqArg  { double f[64]; };

// ---------------- helpers ----------------
__device__ __forceinline__ float4 ld4s(const float* p) { return *reinterpret_cast<const float4*>(p); }
__device__ __forceinline__ void   st4s(float* p, float4 v) { *reinterpret_cast<float4*>(p) = v; }
__device__ __forceinline__ float2 ld2s(const float* p) { return *reinterpret_cast<const float2*>(p); }
__device__ __forceinline__ float4 ld4g(const float* __restrict__ p) { return *reinterpret_cast<const float4*>(p); }

__device__ __forceinline__ float fast_sig(float x)  { return 1.f / (1.f + __expf(-x)); }
__device__ __forceinline__ float fast_tanh(float x) { float e = __expf(2.f * x); return 1.f - 2.f / (e + 1.f); }

// window select: element at position idx relative to C[0]; idx in [-4, 8)
__device__ __forceinline__ float wselA(const float* L, const float* C, const float* R, int idx) {
    return (idx < 0) ? L[idx + 4] : ((idx < 4) ? C[idx] : R[idx - 4]);
}

// ---------------- kernel A: Student-t marginal fit ----------------
__global__ __launch_bounds__(256) void fit_kernel(const float* __restrict__ xh,
                                                  float* __restrict__ loc,
                                                  float* __restrict__ scalef) {
    int gid = blockIdx.x * 256 + threadIdx.x;       // 0..4095  (b*128+d)
    int b = gid >> 7, d = gid & 127;
    const float* p = xh + (size_t)b * 192 * 128 + d;
    float s = 0.f;
    for (int t = 0; t < 192; ++t) s += p[t * 128];
    float m = s * (1.0f / 192.0f);
    float v = 0.f;
    for (int t = 0; t < 192; ++t) {
        float c = p[t * 128] - m; c *= c;
        v = (t == 0) ? c : 0.94f * v + (1.0f - 0.94f) * c;
    }
    float sc = sqrtf(v * 0.5f);
    loc[gid] = m;
    scalef[gid] = fmaxf(sc, 1e-5f);
}

// ---------------- kernel B: per-t diffusion embedding -> cond[6][32] ----------------
__global__ __launch_bounds__(256) void temb_kernel(
    const float* __restrict__ w1, const float* __restrict__ b1,
    const float* __restrict__ w2, const float* __restrict__ b2,
    const float* __restrict__ wt, const float* __restrict__ bt,
    float* __restrict__ cond_all, FreqArg fq) {
    int t = blockIdx.x;
    int tid = threadIdx.x;
    __shared__ float pe[128], te1[512], te2[512];
    if (tid < 64) {
        double e = (double)t * fq.f[tid];
        pe[tid]      = (float)sin(e);
        pe[tid + 64] = (float)cos(e);
    }
    __syncthreads();
    for (int j = tid; j < 512; j += 256) {
        float acc = b1[j];
        for (int k = 0; k < 128; ++k) acc += pe[k] * w1[k * 512 + j];
        te1[j] = acc / (1.f + expf(-acc));
    }
    __syncthreads();
    for (int j = tid; j < 512; j += 256) {
        float acc = b2[j];
        for (int k = 0; k < 512; ++k) acc += te1[k] * w2[k * 512 + j];
        te2[j] = acc / (1.f + expf(-acc));
    }
    __syncthreads();
    if (tid < 192) {
        int l = tid >> 5, c = tid & 31;
        float acc = bt[l * 32 + c];
        const float* w = wt + (size_t)l * 512 * 32 + c;
        for (int k = 0; k < 512; ++k) acc += te2[k] * w[k * 32];
        cond_all[t * 192 + tid] = acc;
    }
}

// ---------------- staging: transposed weight layouts ----------------
// wdT [96 ck][64 o]  at wbuf+0     : wdT[rem*64+o] = wdil[o*96+rem]
// wT  [32 c ][64 o]  at wbuf+6144  : wT[c*64+o]    = wout[o*32+c]
__device__ __forceinline__ void stage_wd_wt(const float* __restrict__ lyr_wdil,
                                            const float* __restrict__ lyr_wout,
                                            int li, float* wbuf, int t, int nt) {
    const float* wd = lyr_wdil + (size_t)li * 6144;
    const float* wo = lyr_wout + (size_t)li * 2048;
    for (int i4 = t; i4 < 1536; i4 += nt) {
        int i = i4 * 4; int o0 = i & 63; int rem = i >> 6;
        float4 v;
        v.x = wd[(o0 + 0) * 96 + rem]; v.y = wd[(o0 + 1) * 96 + rem];
        v.z = wd[(o0 + 2) * 96 + rem]; v.w = wd[(o0 + 3) * 96 + rem];
        st4s(wbuf + i, v);
    }
    for (int i4 = t; i4 < 512; i4 += nt) {
        int i = i4 * 4; int o0 = i & 63; int c = i >> 6;
        float4 v;
        v.x = wo[(o0 + 0) * 32 + c]; v.y = wo[(o0 + 1) * 32 + c];
        v.z = wo[(o0 + 2) * 32 + c]; v.w = wo[(o0 + 3) * 32 + c];
        st4s(wbuf + 6144 + i, v);
    }
}

// w1T [32 c2][32 c]  at wbuf+0    : w1T[c2*32+c] = w_o1[c*32+c2]
// w2T [32 c ][128 d] at wbuf+1024 : w2T[c*128+d] = w_o2[d*32+c]
__device__ __forceinline__ void stage_head(const float* __restrict__ w_o1,
                                           const float* __restrict__ w_o2,
                                           float* wbuf, int t, int nt) {
    for (int i4 = t; i4 < 256; i4 += nt) {
        int i = i4 * 4; int c0 = i & 31; int c2 = i >> 5;
        float4 v;
        v.x = w_o1[(c0 + 0) * 32 + c2]; v.y = w_o1[(c0 + 1) * 32 + c2];
        v.z = w_o1[(c0 + 2) * 32 + c2]; v.w = w_o1[(c0 + 3) * 32 + c2];
        st4s(wbuf + i, v);
    }
    for (int i4 = t; i4 < 1024; i4 += nt) {
        int i = i4 * 4; int d0 = i & 127; int c = i >> 7;
        float4 v;
        v.x = w_o2[(d0 + 0) * 32 + c]; v.y = w_o2[(d0 + 1) * 32 + c];
        v.z = w_o2[(d0 + 2) * 32 + c]; v.w = w_o2[(d0 + 3) * 32 + c];
        st4s(wbuf + 1024 + i, v);
    }
}

// ---------------- conv layer (specialized on dilation D) ----------------
template <int D>
__device__ __forceinline__ void conv_layer(const float* wdT, const float* ssbP, float* convs,
                                           const float* __restrict__ lyr_bdil, int li,
                                           int op, int hh0) {
    const int o0 = 2 * op;
    const float bd0 = lyr_bdil[li * 64 + o0];
    const float bd1 = lyr_bdil[li * 64 + o0 + 1];
    float a0[4] = {bd0, bd0, bd0, bd0};
    float a1[4] = {bd1, bd1, bd1, bd1};
    const float* base = ssbP + 4 + hh0;
#pragma unroll 4
    for (int c = 0; c < 32; ++c) {
        const float* bc = base + c * 36;
        float cv[4]; { float4 v = ld4s(bc); cv[0] = v.x; cv[1] = v.y; cv[2] = v.z; cv[3] = v.w; }
        if constexpr (D <= 4) {
            float lv[4], rv[4];
            { float4 v = ld4s(bc - 4); lv[0] = v.x; lv[1] = v.y; lv[2] = v.z; lv[3] = v.w; }
            { float4 v = ld4s(bc + 4); rv[0] = v.x; rv[1] = v.y; rv[2] = v.z; rv[3] = v.w; }
            float2 w0 = ld2s(wdT + (3 * c + 0) * 64 + o0);
            float2 w1 = ld2s(wdT + (3 * c + 1) * 64 + o0);
            float2 w2 = ld2s(wdT + (3 * c + 2) * 64 + o0);
#pragma unroll
            for (int j = 0; j < 4; ++j) {
                float xm = wselA(lv, cv, rv, j - D);
                float xc = cv[j];
                float xp = wselA(lv, cv, rv, j + D);
                a0[j] += w0.x * xm + w1.x * xc + w2.x * xp;
                a1[j] += w0.y * xm + w1.y * xc + w2.y * xp;
            }
        } else if constexpr (D == 8 || D == 16) {
            float lv[4] = {0.f, 0.f, 0.f, 0.f}, rv[4] = {0.f, 0.f, 0.f, 0.f};
            if constexpr (D == 8) {
                if (hh0 >= 4)  { float4 v = ld4s(bc - 8);  lv[0] = v.x; lv[1] = v.y; lv[2] = v.z; lv[3] = v.w; }
                { float4 v = ld4s(bc + 8);  rv[0] = v.x; rv[1] = v.y; rv[2] = v.z; rv[3] = v.w; }
            } else {
                if (hh0 >= 12) { float4 v = ld4s(bc - 16); lv[0] = v.x; lv[1] = v.y; lv[2] = v.z; lv[3] = v.w; }
                if (hh0 <= 12) { float4 v = ld4s(bc + 16); rv[0] = v.x; rv[1] = v.y; rv[2] = v.z; rv[3] = v.w; }
            }
            float2 w0 = ld2s(wdT + (3 * c + 0) * 64 + o0);
            float2 w1 = ld2s(wdT + (3 * c + 1) * 64 + o0);
            float2 w2 = ld2s(wdT + (3 * c + 2) * 64 + o0);
#pragma unroll
            for (int j = 0; j < 4; ++j) {
                a0[j] += w0.x * lv[j] + w1.x * cv[j] + w2.x * rv[j];
                a1[j] += w0.y * lv[j] + w1.y * cv[j] + w2.y * rv[j];
            }
        } else { // D == 32: side taps always out of range -> center only
            float2 w1 = ld2s(wdT + (3 * c + 1) * 64 + o0);
#pragma unroll
            for (int j = 0; j < 4; ++j) {
                a0[j] += w1.x * cv[j];
                a1[j] += w1.y * cv[j];
            }
        }
    }
    st4s(convs + o0 * 28 + hh0,       make_float4(a0[0], a0[1], a0[2], a0[3]));
    st4s(convs + (o0 + 1) * 28 + hh0, make_float4(a1[0], a1[1], a1[2], a1[3]));
}

// ---------------- kernel C: full 50-step diffusion + output transform ----------------
__global__ __launch_bounds__(256, 2) void diffusion_kernel(
    const float* __restrict__ z_init, const float* __restrict__ noise,
    const float* __restrict__ w_in,   const float* __restrict__ b_in,
    const float* __restrict__ lyr_wdil, const float* __restrict__ lyr_bdil,
    const float* __restrict__ lyr_wout, const float* __restrict__ lyr_bout,
    const float* __restrict__ w_o1, const float* __restrict__ b_o1,
    const float* __restrict__ w_o2, const float* __restrict__ b_o2,
    const float* __restrict__ cond_all, const float* __restrict__ loc,
    const float* __restrict__ scalef, float* __restrict__ out, SchedArg sc) {

    __shared__ __align__(16) float xs[3072];      // [128][24]
    __shared__ __align__(16) float winT[4096];    // [128 k][32 c]
    __shared__ __align__(16) float hs[768];       // [32][24]
    __shared__ __align__(16) float ssbP[1152];    // [32][36]; data cols 4..27, pads zero
    __shared__ __align__(16) float convs[1792];   // [64][28]; data cols 0..23
    __shared__ __align__(16) float skips[768];    // [32][24]
    __shared__ __align__(16) float wbuf[8192];    // wdT[96][64] + wT[32][64] | w1T+w2T

    const int tid = threadIdx.x;
    const int bb  = blockIdx.x;

    // ---- init: xs, winT, ssbP pads ----
    for (int i4 = tid; i4 < 768; i4 += 256)
        st4s(xs + i4 * 4, ld4g(z_init + (size_t)bb * ELEMS + i4 * 4));
    for (int i4 = tid; i4 < 1024; i4 += 256) {    // winT[k*32+c] = w_in[c*128+k]
        int i = i4 * 4; int c0 = i & 31; int k = i >> 5;
        float4 v;
        v.x = w_in[(c0 + 0) * 128 + k]; v.y = w_in[(c0 + 1) * 128 + k];
        v.z = w_in[(c0 + 2) * 128 + k]; v.w = w_in[(c0 + 3) * 128 + k];
        st4s(winT + i, v);
    }
    for (int i = tid; i < 1152; i += 256) ssbP[i] = 0.f;
    __syncthreads();

    const int lc  = tid & 31;       // c / op / dg depending on phase
    const int hg  = tid >> 5;       // 0..5 when tid < 192
    const int hh0 = 4 * hg;
    const bool act192 = (tid < 192);

#pragma unroll 1
    for (int step = 0; step < T_STEPS; ++step) {
        const int t = T_STEPS - 1 - step;

        // ---- phase 1: h = relu(W_in @ x + b_in)  |  wave3: stage layer-0 weights ----
        if (act192) {
            float bv = b_in[lc];
            float a[4] = {bv, bv, bv, bv};
#pragma unroll 4
            for (int k = 0; k < 128; ++k) {
                float w = winT[k * 32 + lc];
                float4 xv = ld4s(xs + k * 24 + hh0);
                a[0] += w * xv.x; a[1] += w * xv.y; a[2] += w * xv.z; a[3] += w * xv.w;
            }
#pragma unroll
            for (int j = 0; j < 4; ++j) a[j] = fmaxf(a[j], 0.f);
            float cv = cond_all[t * 192 + lc];
            st4s(hs + lc * 24 + hh0,       make_float4(a[0], a[1], a[2], a[3]));
            st4s(ssbP + lc * 36 + 4 + hh0, make_float4(a[0] + cv, a[1] + cv, a[2] + cv, a[3] + cv));
            st4s(skips + lc * 24 + hh0,    make_float4(0.f, 0.f, 0.f, 0.f));
        } else {
            stage_wd_wt(lyr_wdil, lyr_wout, 0, wbuf, tid - 192, 64);
        }
        __syncthreads();

        // ---- residual layers (fully specialized) ----
#define RES_LAYER(LI, DD)                                                                 \
        {                                                                                 \
            if (act192) conv_layer<DD>(wbuf, ssbP, convs, lyr_bdil, LI, lc, hh0);         \
            __syncthreads();                                                              \
            if (act192) {                                                                 \
                float4 g = ld4s(convs + lc * 28 + hh0);                                   \
                float4 f = ld4s(convs + (32 + lc) * 28 + hh0);                            \
                float4 r;                                                                 \
                r.x = fast_tanh(f.x) * fast_sig(g.x);                                     \
                r.y = fast_tanh(f.y) * fast_sig(g.y);                                     \
                r.z = fast_tanh(f.z) * fast_sig(g.z);                                     \
                r.w = fast_tanh(f.w) * fast_sig(g.w);                                     \
                st4s(convs + lc * 28 + hh0, r);                                           \
            }                                                                             \
            __syncthreads();                                                              \
            if (act192) {                                                                 \
                const float* wT = wbuf + 6144;                                            \
                const int o0 = 2 * lc;                                                    \
                float b0 = lyr_bout[LI * 64 + o0], b1 = lyr_bout[LI * 64 + o0 + 1];       \
                float a0[4] = {b0, b0, b0, b0};                                           \
                float a1[4] = {b1, b1, b1, b1};                                           \
                _Pragma("unroll 4")                                                       \
                for (int c = 0; c < 32; ++c) {                                            \
                    float2 w = ld2s(wT + c * 64 + o0);                                    \
                    float4 av = ld4s(convs + c * 28 + hh0);                               \
                    a0[0] += w.x * av.x; a0[1] += w.x * av.y;                             \
                    a0[2] += w.x * av.z; a0[3] += w.x * av.w;                             \
                    a1[0] += w.y * av.x; a1[1] += w.y * av.y;                             \
                    a1[2] += w.y * av.z; a1[3] += w.y * av.w;                             \
                }                                                                         \
                if (lc < 16) {                                                            \
                    if (LI < 5) {                                                         \
                        float4 h0 = ld4s(hs + o0 * 24 + hh0);                             \
                        float4 h1 = ld4s(hs + (o0 + 1) * 24 + hh0);                       \
                        h0.x = (h0.x + a0[0]) * RS2; h0.y = (h0.y + a0[1]) * RS2;         \
                        h0.z = (h0.z + a0[2]) * RS2; h0.w = (h0.w + a0[3]) * RS2;         \
                        h1.x = (h1.x + a1[0]) * RS2; h1.y = (h1.y + a1[1]) * RS2;         \
                        h1.z = (h1.z + a1[2]) * RS2; h1.w = (h1.w + a1[3]) * RS2;         \
                        st4s(hs + o0 * 24 + hh0, h0);                                     \
                        st4s(hs + (o0 + 1) * 24 + hh0, h1);                               \
                        float c0 = cond_all[t * 192 + (LI + 1) * 32 + o0];                \
                        float c1 = cond_all[t * 192 + (LI + 1) * 32 + o0 + 1];            \
                        st4s(ssbP + o0 * 36 + 4 + hh0,                                    \
                             make_float4(h0.x + c0, h0.y + c0, h0.z + c0, h0.w + c0));    \
                        st4s(ssbP + (o0 + 1) * 36 + 4 + hh0,                              \
                             make_float4(h1.x + c1, h1.y + c1, h1.z + c1, h1.w + c1));    \
                    }                                                                     \
                } else {                                                                  \
                    int so = o0 - 32;                                                     \
                    float4 s0 = ld4s(skips + so * 24 + hh0);                              \
                    float4 s1 = ld4s(skips + (so + 1) * 24 + hh0);                        \
                    s0.x += a0[0]; s0.y += a0[1]; s0.z += a0[2]; s0.w += a0[3];           \
                    s1.x += a1[0]; s1.y += a1[1]; s1.z += a1[2]; s1.w += a1[3];           \
                    st4s(skips + so * 24 + hh0, s0);                                      \
                    st4s(skips + (so + 1) * 24 + hh0, s1);                                \
                }                                                                         \
            }                                                                             \
            __syncthreads();                                                              \
            if (LI < 5) stage_wd_wt(lyr_wdil, lyr_wout, LI + 1, wbuf, tid, 256);          \
            else        stage_head(w_o1, w_o2, wbuf, tid, 256);                           \
            __syncthreads();                                                              \
        }

        RES_LAYER(0, 1)
        RES_LAYER(1, 2)
        RES_LAYER(2, 4)
        RES_LAYER(3, 8)
        RES_LAYER(4, 16)
        RES_LAYER(5, 32)
#undef RES_LAYER

        // ---- skip head: s = relu(b_o1 + W_o1 @ (skip/sqrt(6))) -> hs ----
        if (act192) {
            const float* w1T = wbuf;
            float a[4] = {0.f, 0.f, 0.f, 0.f};
#pragma unroll 4
            for (int c2 = 0; c2 < 32; ++c2) {
                float w = w1T[c2 * 32 + lc];
                float4 sv = ld4s(skips + c2 * 24 + hh0);
                a[0] += w * sv.x; a[1] += w * sv.y; a[2] += w * sv.z; a[3] += w * sv.w;
            }
            float bv = b_o1[lc];
            float4 r;
            r.x = fmaxf(bv + INV_SQRT_L * a[0], 0.f);
            r.y = fmaxf(bv + INV_SQRT_L * a[1], 0.f);
            r.z = fmaxf(bv + INV_SQRT_L * a[2], 0.f);
            r.w = fmaxf(bv + INV_SQRT_L * a[3], 0.f);
            st4s(hs + lc * 24 + hh0, r);
        }
        __syncthreads();

        // ---- eps = b_o2 + W_o2 @ s, fused DDPM update ----
        if (act192) {
            const float* w2T = wbuf + 1024;
            const int d0 = 4 * lc;
            float e0[4], e1[4], e2[4], e3[4];
            {
                float q0 = b_o2[d0], q1 = b_o2[d0 + 1], q2 = b_o2[d0 + 2], q3 = b_o2[d0 + 3];
#pragma unroll
                for (int j = 0; j < 4; ++j) { e0[j] = q0; e1[j] = q1; e2[j] = q2; e3[j] = q3; }
            }
#pragma unroll 4
            for (int c = 0; c < 32; ++c) {
                float4 w = ld4s(w2T + c * 128 + d0);
                float4 sv = ld4s(hs + c * 24 + hh0);
                e0[0] += w.x * sv.x; e0[1] += w.x * sv.y; e0[2] += w.x * sv.z; e0[3] += w.x * sv.w;
                e1[0] += w.y * sv.x; e1[1] += w.y * sv.y; e1[2] += w.y * sv.z; e1[3] += w.y * sv.w;
                e2[0] += w.z * sv.x; e2[1] += w.z * sv.y; e2[2] += w.z * sv.z; e2[3] += w.z * sv.w;
                e3[0] += w.w * sv.x; e3[1] += w.w * sv.y; e3[2] += w.w * sv.z; e3[3] += w.w * sv.w;
            }
            const float cx0 = sc.cx0[t], cxt = sc.cxt[t], sig = sc.sig[t];
            const float s1m = sc.s1m[t], isab = sc.isab[t];
            const float* nzp = noise + ((size_t)step * NB + bb) * ELEMS;
#pragma unroll
            for (int i = 0; i < 4; ++i) {
                const float* ei = (i == 0) ? e0 : (i == 1) ? e1 : (i == 2) ? e2 : e3;
                int idx = (d0 + i) * 24 + hh0;
                float4 xv = ld4s(xs + idx);
                float4 nz = ld4g(nzp + idx);
                float4 r;
                {
                    float x0;
                    x0 = fminf(fmaxf((xv.x - s1m * ei[0]) * isab, -1.f), 1.f);
                    r.x = cx0 * x0 + cxt * xv.x + sig * nz.x;
                    x0 = fminf(fmaxf((xv.y - s1m * ei[1]) * isab, -1.f), 1.f);
                    r.y = cx0 * x0 + cxt * xv.y + sig * nz.y;
                    x0 = fminf(fmaxf((xv.z - s1m * ei[2]) * isab, -1.f), 1.f);
                    r.z = cx0 * x0 + cxt * xv.z + sig * nz.z;
                    x0 = fminf(fmaxf((xv.w - s1m * ei[3]) * isab, -1.f), 1.f);
                    r.w = cx0 * x0 + cxt * xv.w + sig * nz.w;
                }
                st4s(xs + idx, r);
            }
        }
        __syncthreads();
    }

    // ---- epilogue: Gaussian -> Student-t4, coalesced transposed write ----
    {
        const int b = bb & 31;
        const int dd0 = (tid & 31) * 4;
        const int hr = tid >> 5;             // 0..7
        float4 l4 = ld4g(loc + b * 128 + dd0);
        float4 s4 = ld4g(scalef + b * 128 + dd0);
#pragma unroll
        for (int p = 0; p < 3; ++p) {
            int hh = hr + 8 * p;
            float zv[4];
#pragma unroll
            for (int i = 0; i < 4; ++i) zv[i] = xs[(dd0 + i) * 24 + hh];
            float4 o4;
            float lv[4] = {l4.x, l4.y, l4.z, l4.w};
            float sv[4] = {s4.x, s4.y, s4.z, s4.w};
            float ov[4];
#pragma unroll
            for (int i = 0; i < 4; ++i) {
                float u = 0.5f * (1.f + erff(zv[i] * RS2));
                u = fminf(fmaxf(u, 1e-6f), 1.f - 1e-6f);
                float a4 = fminf(fmaxf(4.f * u * (1.f - u), 1e-12f), 1.f);
                float rr = sqrtf(a4);
                float q = 2.f * sqrtf(fmaxf(cosf(acosf(rr) * (1.f / 3.f)) / rr - 1.f, 0.f));
                float tstd = (u < 0.5f) ? -q : q;
                ov[i] = lv[i] + sv[i] * tstd;
            }
            o4.x = ov[0]; o4.y = ov[1]; o4.z = ov[2]; o4.w = ov[3];
            *reinterpret_cast<float4*>(out + ((size_t)bb * 24 + hh) * 128 + dd0) = o4;
        }
    }
}

// ---------------- host ----------------
extern "C" void kernel_launch(void* const* d_in, const int* in_sizes, int n_in,
                              void* d_out, int out_size, void* d_ws, size_t ws_size,
                              hipStream_t stream) {
    const float* x_hist  = (const float*)d_in[0];
    const float* z_init  = (const float*)d_in[1];
    const float* noise   = (const float*)d_in[2];
    const float* w_in    = (const float*)d_in[3];
    const float* b_in    = (const float*)d_in[4];
    const float* temb_w1 = (const float*)d_in[5];
    const float* temb_b1 = (const float*)d_in[6];
    const float* temb_w2 = (const float*)d_in[7];
    const float* temb_b2 = (const float*)d_in[8];
    const float* lyr_wt  = (const float*)d_in[9];
    const float* lyr_bt  = (const float*)d_in[10];
    const float* lyr_wdil= (const float*)d_in[11];
    const float* lyr_bdil= (const float*)d_in[12];
    const float* lyr_wout= (const float*)d_in[13];
    const float* lyr_bout= (const float*)d_in[14];
    const float* w_o1    = (const float*)d_in[15];
    const float* b_o1    = (const float*)d_in[16];
    const float* w_o2    = (const float*)d_in[17];
    const float* b_o2    = (const float*)d_in[18];
    float* out = (float*)d_out;

    float* loc      = (float*)d_ws;            // 4096
    float* scalef   = loc + 4096;              // 4096
    float* cond_all = scalef + 4096;           // 50*192 = 9600

    SchedArg sa;
    double abar = 1.0;
    for (int t = 0; t < T_STEPS; ++t) {
        double beta  = 1e-4 + (0.1 - 1e-4) * ((double)t / 49.0);
        double alpha = 1.0 - beta;
        double abprev = abar;
        abar *= alpha;
        sa.cx0[t]  = (float)(beta * sqrt(abprev) / (1.0 - abar));
        sa.cxt[t]  = (float)((1.0 - abprev) * sqrt(alpha) / (1.0 - abar));
        double pv  = beta * (1.0 - abprev) / (1.0 - abar);
        sa.sig[t]  = (t > 0) ? (float)sqrt(pv) : 0.f;
        sa.s1m[t]  = (float)sqrt(1.0 - abar);
        sa.isab[t] = (float)(1.0 / sqrt(abar));
    }
    FreqArg fa;
    for (int j = 0; j < 64; ++j) fa.f[j] = pow(10.0, (double)j * 4.0 / 63.0);

    fit_kernel<<<16, 256, 0, stream>>>(x_hist, loc, scalef);
    temb_kernel<<<T_STEPS, 256, 0, stream>>>(temb_w1, temb_b1, temb_w2, temb_b2,
                                             lyr_wt, lyr_bt, cond_all, fa);
    diffusion_kernel<<<NB, 256, 0, stream>>>(z_init, noise, w_in, b_in,
                                             lyr_wdil, lyr_bdil, lyr_wout, lyr_bout,
                                             w_o1, b_o1, w_o2, b_o2,
                                             cond_all, loc, scalef, out, sa);
}

// Round 3
// 3189.110 us; speedup vs baseline: 1.1283x; 1.1283x over previous
//
#include <hip/hip_runtime.h>
#include <math.h>

// ---------------- constants ----------------
#define T_STEPS 50
#define NB 512
#define RS2 0.70710678118654752f
#define INV_SQRT_L 0.40824829046386302f

// wpack layout (floats, relative to wpack base)
#define WPH1   0        // [8 wv][128 k][4 ci]            = 4096
#define WCONV  4096     // [6 l][8 wv][96 ck][8 oi]       = 36864
#define WOUT   40960    // [6 l][8 wv][32 c][8 oi]        = 12288
#define WO1    53248    // [8 wv][32 c2][4 ci]            = 1024
#define WO2    54272    // [8 wv][32 c][16 di]            = 4096
#define WTOTAL 58368
#define WS_WPACK_OFF 18432   // floats: loc 4096 + scale 4096 + cond 9600 -> rounded

struct SchedArg { float cx0[T_STEPS], cxt[T_STEPS], sig[T_STEPS], s1m[T_STEPS], isab[T_STEPS]; };
struct FreqArg  { double f[64]; };

__device__ __forceinline__ float4 ld4s(const float* p) { return *reinterpret_cast<const float4*>(p); }
__device__ __forceinline__ void   st4s(float* p, float4 v) { *reinterpret_cast<float4*>(p) = v; }
__device__ __forceinline__ float4 ld4g(const float* __restrict__ p) { return *reinterpret_cast<const float4*>(p); }
__device__ __forceinline__ float fast_sig(float x)  { return 1.f / (1.f + __expf(-x)); }
__device__ __forceinline__ float fast_tanh(float x) { float e = __expf(2.f * x); return 1.f - 2.f / (e + 1.f); }

// ---------------- kernel A: Student-t marginal fit ----------------
__global__ __launch_bounds__(256) void fit_kernel(const float* __restrict__ xh,
                                                  float* __restrict__ loc,
                                                  float* __restrict__ scalef) {
    int gid = blockIdx.x * 256 + threadIdx.x;
    int b = gid >> 7, d = gid & 127;
    const float* p = xh + (size_t)b * 192 * 128 + d;
    float s = 0.f;
    for (int t = 0; t < 192; ++t) s += p[t * 128];
    float m = s * (1.0f / 192.0f);
    float v = 0.f;
    for (int t = 0; t < 192; ++t) {
        float c = p[t * 128] - m; c *= c;
        v = (t == 0) ? c : 0.94f * v + (1.0f - 0.94f) * c;
    }
    loc[gid] = m;
    scalef[gid] = fmaxf(sqrtf(v * 0.5f), 1e-5f);
}

// ---------------- kernel B: per-t embedding -> cond[6][32] ----------------
__global__ __launch_bounds__(256) void temb_kernel(
    const float* __restrict__ w1, const float* __restrict__ b1,
    const float* __restrict__ w2, const float* __restrict__ b2,
    const float* __restrict__ wt, const float* __restrict__ bt,
    float* __restrict__ cond_all, FreqArg fq) {
    int t = blockIdx.x;
    int tid = threadIdx.x;
    __shared__ float pe[128], te1[512], te2[512];
    if (tid < 64) {
        double e = (double)t * fq.f[tid];
        pe[tid]      = (float)sin(e);
        pe[tid + 64] = (float)cos(e);
    }
    __syncthreads();
    for (int j = tid; j < 512; j += 256) {
        float acc = b1[j];
        for (int k = 0; k < 128; ++k) acc += pe[k] * w1[k * 512 + j];
        te1[j] = acc / (1.f + expf(-acc));
    }
    __syncthreads();
    for (int j = tid; j < 512; j += 256) {
        float acc = b2[j];
        for (int k = 0; k < 512; ++k) acc += te1[k] * w2[k * 512 + j];
        te2[j] = acc / (1.f + expf(-acc));
    }
    __syncthreads();
    if (tid < 192) {
        int l = tid >> 5, c = tid & 31;
        float acc = bt[l * 32 + c];
        const float* w = wt + (size_t)l * 512 * 32 + c;
        for (int k = 0; k < 512; ++k) acc += te2[k] * w[k * 32];
        cond_all[t * 192 + tid] = acc;
    }
}

// ---------------- kernel P: pre-transpose weights into wpack ----------------
__global__ __launch_bounds__(256) void prep_kernel(
    const float* __restrict__ w_in, const float* __restrict__ lyr_wdil,
    const float* __restrict__ lyr_wout, const float* __restrict__ w_o1,
    const float* __restrict__ w_o2, float* __restrict__ wpack) {
    int i = blockIdx.x * 256 + threadIdx.x;
    if (i >= WTOTAL) return;
    float v;
    if (i < WCONV) {                       // wph1[wv][k][ci]
        int wv = i >> 9, r = i & 511, k = r >> 2, ci = r & 3;
        v = w_in[(4 * wv + ci) * 128 + k];
    } else if (i < WOUT) {                 // wconv[l][wv][ck][oi]
        int j = i - WCONV;
        int l = j / 6144, r1 = j % 6144;
        int wv = r1 / 768, r2 = r1 % 768;
        int ck = r2 >> 3, oi = r2 & 7;
        int c = ck / 3, kk = ck - c * 3;
        int o = (oi < 4) ? (4 * wv + oi) : (32 + 4 * wv + oi - 4);
        v = lyr_wdil[l * 6144 + o * 96 + c * 3 + kk];
    } else if (i < WO1) {                  // woutT[l][wv][c][oi]
        int j = i - WOUT;
        int l = j / 2048, r1 = j % 2048;
        int wv = r1 / 256, r2 = r1 % 256;
        int c = r2 >> 3, oi = r2 & 7;
        int o = (oi < 4) ? (4 * wv + oi) : (32 + 4 * wv + oi - 4);
        v = lyr_wout[l * 2048 + o * 32 + c];
    } else if (i < WO2) {                  // who1[wv][c2][ci]
        int j = i - WO1;
        int wv = j >> 7, r1 = j & 127, c2 = r1 >> 2, ci = r1 & 3;
        v = w_o1[(4 * wv + ci) * 32 + c2];
    } else {                               // who2[wv][c][di]
        int j = i - WO2;
        int wv = j >> 9, r1 = j & 511, c = r1 >> 4, di = r1 & 15;
        v = w_o2[(16 * wv + di) * 32 + c];
    }
    wpack[i] = v;
}

// ---------------- kernel C: 50-step diffusion, 2 rows/block ----------------
__global__ __launch_bounds__(512) void diffusion_kernel(
    const float* __restrict__ z_init, const float* __restrict__ noise,
    const float* __restrict__ b_in,  const float* __restrict__ lyr_bdil,
    const float* __restrict__ lyr_bout, const float* __restrict__ b_o1,
    const float* __restrict__ b_o2, const float* __restrict__ cond_all,
    const float* __restrict__ wpack, const float* __restrict__ loc,
    const float* __restrict__ scalef, float* __restrict__ out, SchedArg sc) {

    __shared__ __align__(16) float xs[2 * 32 * 128];   // [r][h 32][d 128], chunk-swizzled
    __shared__ __align__(16) float hsb[2 * 32 * 32];   // [r][h][c], chunk-swizzled
    __shared__ __align__(16) float actb[2 * 32 * 32];
    __shared__ __align__(16) float skb[2 * 32 * 32];

    const int tid = threadIdx.x;
    const int wv  = __builtin_amdgcn_readfirstlane(tid >> 6);   // wave id 0..7 (uniform)
    const int lane = tid & 63;
    const int r = lane >> 5;           // row within block pair
    const int h = lane & 31;           // 0..31, valid < 24
    const bool vh = (h < 24);
    const int bb = blockIdx.x;         // 0..255
    const int hx = (h & 7);            // swizzle key

    // ---- init: stage z_init -> xs (transposed+swizzled), zero pads+buffers ----
    for (int i = tid; i < 6144; i += 512) {
        int rr = i / 3072, rem = i - rr * 3072;
        int d = rem / 24, hh = rem - d * 24;
        int ch = d >> 2, e = d & 3;
        int swz = (ch & 24) | ((ch ^ hh) & 7);
        xs[rr * 4096 + hh * 128 + swz * 4 + e] = z_init[(size_t)bb * 6144 + i];
    }
    for (int i = tid; i < 2048; i += 512) {            // zero xs pad rows h=24..31
        int rr = i >> 10, rem = i & 1023;
        xs[rr * 4096 + (24 + (rem >> 7)) * 128 + (rem & 127)] = 0.f;
    }
    for (int i = tid; i < 2048; i += 512) { hsb[i] = 0.f; actb[i] = 0.f; skb[i] = 0.f; }
    __syncthreads();

    const float* hsr  = hsb  + r * 1024 + h * 32;
    const float* actr = actb + r * 1024 + h * 32;
    float*       skr  = skb  + r * 1024 + h * 32;
    float*       xsr  = xs   + r * 4096 + h * 128;

    for (int step = 0; step < T_STEPS; ++step) {
        const int t = T_STEPS - 1 - step;

        // ---- P1: h = relu(W_in @ x + b_in); skip = 0 ----
        {
            const float* wp = wpack + WPH1 + wv * 512;       // [k][ci]
            float a0 = b_in[4 * wv + 0], a1 = b_in[4 * wv + 1];
            float a2 = b_in[4 * wv + 2], a3 = b_in[4 * wv + 3];
            for (int d4 = 0; d4 < 32; ++d4) {
                float4 xv = ld4s(xsr + (((d4 & 24) | ((d4 ^ h) & 7)) << 2));
                const float* wk = wp + d4 * 16;
#pragma unroll
                for (int e = 0; e < 4; ++e) {
                    float x = (&xv.x)[e];
                    a0 += wk[e * 4 + 0] * x; a1 += wk[e * 4 + 1] * x;
                    a2 += wk[e * 4 + 2] * x; a3 += wk[e * 4 + 3] * x;
                }
            }
            float4 hv = make_float4(fmaxf(a0, 0.f), fmaxf(a1, 0.f), fmaxf(a2, 0.f), fmaxf(a3, 0.f));
            st4s((float*)hsr + ((wv ^ h) & 7) * 4, hv);
            st4s(skr + ((wv ^ h) & 7) * 4, make_float4(0.f, 0.f, 0.f, 0.f));
        }
        __syncthreads();

        // ---- 6 residual layers ----
        for (int li = 0; li < 6; ++li) {
            const int D = 1 << li;
            // conv (+cond fused, gate/filt in-wave) -> act
            {
                const float* wp = wpack + WCONV + (li * 8 + wv) * 768;   // [ck][oi]
                float ag0 = lyr_bdil[li * 64 + 4 * wv + 0], ag1 = lyr_bdil[li * 64 + 4 * wv + 1];
                float ag2 = lyr_bdil[li * 64 + 4 * wv + 2], ag3 = lyr_bdil[li * 64 + 4 * wv + 3];
                float af0 = lyr_bdil[li * 64 + 32 + 4 * wv + 0], af1 = lyr_bdil[li * 64 + 32 + 4 * wv + 1];
                float af2 = lyr_bdil[li * 64 + 32 + 4 * wv + 2], af3 = lyr_bdil[li * 64 + 32 + 4 * wv + 3];
                const int rm = h - D, rp = h + D;
                const bool vm = ((unsigned)rm < 24u), vc = vh, vp = ((unsigned)rp < 24u);
                const int rmm = rm & 31, rpp = rp & 31;
                const float* hb = hsb + r * 1024;
                const float* cnd = cond_all + t * 192 + li * 32;
                for (int c4 = 0; c4 < 8; ++c4) {
                    float4 v0 = ld4s(hb + rmm * 32 + (((c4 ^ rmm) & 7) << 2));
                    float4 v1 = ld4s(hb + h   * 32 + (((c4 ^ h)   & 7) << 2));
                    float4 v2 = ld4s(hb + rpp * 32 + (((c4 ^ rpp) & 7) << 2));
                    const float* wc = wp + c4 * 96;
#pragma unroll
                    for (int e = 0; e < 4; ++e) {
                        float cv = cnd[c4 * 4 + e];
                        float x0 = vm ? ((&v0.x)[e] + cv) : 0.f;
                        float x1 = vc ? ((&v1.x)[e] + cv) : 0.f;
                        float x2 = vp ? ((&v2.x)[e] + cv) : 0.f;
                        const float* w3 = wc + e * 24;
                        ag0 += w3[0] * x0 + w3[8]  * x1 + w3[16] * x2;
                        ag1 += w3[1] * x0 + w3[9]  * x1 + w3[17] * x2;
                        ag2 += w3[2] * x0 + w3[10] * x1 + w3[18] * x2;
                        ag3 += w3[3] * x0 + w3[11] * x1 + w3[19] * x2;
                        af0 += w3[4] * x0 + w3[12] * x1 + w3[20] * x2;
                        af1 += w3[5] * x0 + w3[13] * x1 + w3[21] * x2;
                        af2 += w3[6] * x0 + w3[14] * x1 + w3[22] * x2;
                        af3 += w3[7] * x0 + w3[15] * x1 + w3[23] * x2;
                    }
                }
                float4 av;
                av.x = fast_tanh(af0) * fast_sig(ag0);
                av.y = fast_tanh(af1) * fast_sig(ag1);
                av.z = fast_tanh(af2) * fast_sig(ag2);
                av.w = fast_tanh(af3) * fast_sig(ag3);
                st4s((float*)actr + ((wv ^ h) & 7) * 4, av);
            }
            __syncthreads();
            // out-proj: res -> hs RMW, skip -> skips RMW
            {
                const float* wp = wpack + WOUT + (li * 8 + wv) * 256;    // [c][oi]
                float ar0 = lyr_bout[li * 64 + 4 * wv + 0], ar1 = lyr_bout[li * 64 + 4 * wv + 1];
                float ar2 = lyr_bout[li * 64 + 4 * wv + 2], ar3 = lyr_bout[li * 64 + 4 * wv + 3];
                float as0 = lyr_bout[li * 64 + 32 + 4 * wv + 0], as1 = lyr_bout[li * 64 + 32 + 4 * wv + 1];
                float as2 = lyr_bout[li * 64 + 32 + 4 * wv + 2], as3 = lyr_bout[li * 64 + 32 + 4 * wv + 3];
                for (int c4 = 0; c4 < 8; ++c4) {
                    float4 v = ld4s(actr + (((c4 ^ h) & 7) << 2));
                    const float* w4 = wp + c4 * 32;
#pragma unroll
                    for (int e = 0; e < 4; ++e) {
                        float x = (&v.x)[e];
                        const float* w8 = w4 + e * 8;
                        ar0 += w8[0] * x; ar1 += w8[1] * x; ar2 += w8[2] * x; ar3 += w8[3] * x;
                        as0 += w8[4] * x; as1 += w8[5] * x; as2 += w8[6] * x; as3 += w8[7] * x;
                    }
                }
                float* hp = (float*)hsr + ((wv ^ h) & 7) * 4;
                if (li < 5) {
                    float4 hv = ld4s(hp);
                    hv.x = (hv.x + ar0) * RS2; hv.y = (hv.y + ar1) * RS2;
                    hv.z = (hv.z + ar2) * RS2; hv.w = (hv.w + ar3) * RS2;
                    st4s(hp, hv);
                }
                float* sp = skr + ((wv ^ h) & 7) * 4;
                float4 sv = ld4s(sp);
                sv.x += as0; sv.y += as1; sv.z += as2; sv.w += as3;
                st4s(sp, sv);
            }
            __syncthreads();
        }

        // ---- skip head: s = relu(b_o1 + inv6 * W_o1 @ skip) -> hs ----
        {
            const float* wp = wpack + WO1 + wv * 128;   // [c2][ci]
            float a0 = 0.f, a1 = 0.f, a2 = 0.f, a3 = 0.f;
            for (int c4 = 0; c4 < 8; ++c4) {
                float4 v = ld4s(skr + (((c4 ^ h) & 7) << 2));
                const float* w4 = wp + c4 * 16;
#pragma unroll
                for (int e = 0; e < 4; ++e) {
                    float x = (&v.x)[e];
                    a0 += w4[e * 4 + 0] * x; a1 += w4[e * 4 + 1] * x;
                    a2 += w4[e * 4 + 2] * x; a3 += w4[e * 4 + 3] * x;
                }
            }
            float4 s4;
            s4.x = fmaxf(b_o1[4 * wv + 0] + INV_SQRT_L * a0, 0.f);
            s4.y = fmaxf(b_o1[4 * wv + 1] + INV_SQRT_L * a1, 0.f);
            s4.z = fmaxf(b_o1[4 * wv + 2] + INV_SQRT_L * a2, 0.f);
            s4.w = fmaxf(b_o1[4 * wv + 3] + INV_SQRT_L * a3, 0.f);
            st4s((float*)hsr + ((wv ^ h) & 7) * 4, s4);
        }
        __syncthreads();

        // ---- eps = b_o2 + W_o2 @ s, fused DDPM x-update (d-tile 16 per wave) ----
        {
            const float* wp = wpack + WO2 + wv * 512;   // [c][di]
            float acc[16];
#pragma unroll
            for (int di = 0; di < 16; ++di) acc[di] = b_o2[16 * wv + di];
            for (int c4 = 0; c4 < 8; ++c4) {
                float4 v = ld4s(hsr + (((c4 ^ h) & 7) << 2));
                const float* w16 = wp + c4 * 64;
#pragma unroll
                for (int e = 0; e < 4; ++e) {
                    float x = (&v.x)[e];
                    const float* wq = w16 + e * 16;
#pragma unroll
                    for (int di = 0; di < 16; ++di) acc[di] += wq[di] * x;
                }
            }
            const float cx0 = sc.cx0[t], cxt = sc.cxt[t], sig = sc.sig[t];
            const float s1m = sc.s1m[t], isab = sc.isab[t];
            const float* nz = noise + ((size_t)step * NB + bb * 2 + r) * 3072;
            const int hsafe = vh ? h : 0;
#pragma unroll
            for (int j = 0; j < 4; ++j) {
                int d4 = 4 * wv + j;
                float* px = xsr + (((d4 & 24) | ((d4 ^ h) & 7)) << 2);
                float4 xv = ld4s(px);
                float4 rr;
#pragma unroll
                for (int e = 0; e < 4; ++e) {
                    float ev = acc[4 * j + e];
                    float nzv = nz[(16 * wv + 4 * j + e) * 24 + hsafe];
                    nzv = vh ? nzv : 0.f;
                    float xvv = (&xv.x)[e];
                    float x0 = fminf(fmaxf((xvv - s1m * ev) * isab, -1.f), 1.f);
                    (&rr.x)[e] = cx0 * x0 + cxt * xvv + sig * nzv;
                }
                st4s(px, rr);
            }
        }
        __syncthreads();
    }

    // ---- epilogue: Gaussian -> Student-t4, write [S,B,H,D] ----
    if (vh) {
        const int b = (bb * 2 + r) & 31;
#pragma unroll
        for (int j = 0; j < 4; ++j) {
            int d4 = 4 * wv + j;
            float4 zv = ld4s(xsr + (((d4 & 24) | ((d4 ^ h) & 7)) << 2));
            float4 l4 = ld4g(loc + b * 128 + d4 * 4);
            float4 s4 = ld4g(scalef + b * 128 + d4 * 4);
            float4 o4;
#pragma unroll
            for (int e = 0; e < 4; ++e) {
                float u = 0.5f * (1.f + erff((&zv.x)[e] * RS2));
                u = fminf(fmaxf(u, 1e-6f), 1.f - 1e-6f);
                float a4 = fminf(fmaxf(4.f * u * (1.f - u), 1e-12f), 1.f);
                float rr = sqrtf(a4);
                float q = 2.f * sqrtf(fmaxf(cosf(acosf(rr) * (1.f / 3.f)) / rr - 1.f, 0.f));
                float tstd = (u < 0.5f) ? -q : q;
                (&o4.x)[e] = (&l4.x)[e] + (&s4.x)[e] * tstd;
            }
            *reinterpret_cast<float4*>(out + ((size_t)(bb * 2 + r) * 24 + h) * 128 + d4 * 4) = o4;
        }
    }
}

// ---------------- host ----------------
extern "C" void kernel_launch(void* const* d_in, const int* in_sizes, int n_in,
                              void* d_out, int out_size, void* d_ws, size_t ws_size,
                              hipStream_t stream) {
    const float* x_hist  = (const float*)d_in[0];
    const float* z_init  = (const float*)d_in[1];
    const float* noise   = (const float*)d_in[2];
    const float* w_in    = (const float*)d_in[3];
    const float* b_in    = (const float*)d_in[4];
    const float* temb_w1 = (const float*)d_in[5];
    const float* temb_b1 = (const float*)d_in[6];
    const float* temb_w2 = (const float*)d_in[7];
    const float* temb_b2 = (const float*)d_in[8];
    const float* lyr_wt  = (const float*)d_in[9];
    const float* lyr_bt  = (const float*)d_in[10];
    const float* lyr_wdil= (const float*)d_in[11];
    const float* lyr_bdil= (const float*)d_in[12];
    const float* lyr_wout= (const float*)d_in[13];
    const float* lyr_bout= (const float*)d_in[14];
    const float* w_o1    = (const float*)d_in[15];
    const float* b_o1    = (const float*)d_in[16];
    const float* w_o2    = (const float*)d_in[17];
    const float* b_o2    = (const float*)d_in[18];
    float* out = (float*)d_out;

    float* loc      = (float*)d_ws;                    // 4096
    float* scalef   = loc + 4096;                      // 4096
    float* cond_all = scalef + 4096;                   // 9600
    float* wpack    = (float*)d_ws + WS_WPACK_OFF;     // 58368

    SchedArg sa;
    double abar = 1.0;
    for (int t = 0; t < T_STEPS; ++t) {
        double beta  = 1e-4 + (0.1 - 1e-4) * ((double)t / 49.0);
        double alpha = 1.0 - beta;
        double abprev = abar;
        abar *= alpha;
        sa.cx0[t]  = (float)(beta * sqrt(abprev) / (1.0 - abar));
        sa.cxt[t]  = (float)((1.0 - abprev) * sqrt(alpha) / (1.0 - abar));
        double pv  = beta * (1.0 - abprev) / (1.0 - abar);
        sa.sig[t]  = (t > 0) ? (float)sqrt(pv) : 0.f;
        sa.s1m[t]  = (float)sqrt(1.0 - abar);
        sa.isab[t] = (float)(1.0 / sqrt(abar));
    }
    FreqArg fa;
    for (int j = 0; j < 64; ++j) fa.f[j] = pow(10.0, (double)j * 4.0 / 63.0);

    prep_kernel<<<(WTOTAL + 255) / 256, 256, 0, stream>>>(w_in, lyr_wdil, lyr_wout, w_o1, w_o2, wpack);
    fit_kernel<<<16, 256, 0, stream>>>(x_hist, loc, scalef);
    temb_kernel<<<T_STEPS, 256, 0, stream>>>(temb_w1, temb_b1, temb_w2, temb_b2,
                                             lyr_wt, lyr_bt, cond_all, fa);
    diffusion_kernel<<<256, 512, 0, stream>>>(z_init, noise, b_in, lyr_bdil,
                                              lyr_bout, b_o1, b_o2, cond_all,
                                              wpack, loc, scalef, out, sa);
}

// Round 4
// 702.925 us; speedup vs baseline: 5.1192x; 4.5369x over previous
//
#include <hip/hip_runtime.h>
#include <math.h>

// ---------------- constants ----------------
#define T_STEPS 50
#define NB 512
#define RS2 0.70710678118654752f
#define INV_SQRT_L 0.40824829046386302f
#define CZ 48                    // zero column index in hcB
#define WPACK_SHORT_OFF 36864    // d_ws offset in shorts (= float off 18432)

struct SchedArg { float cx0[T_STEPS], cxt[T_STEPS], sig[T_STEPS], s1m[T_STEPS], isab[T_STEPS]; };
struct FreqArg  { double f[64]; };

typedef short bf16x8 __attribute__((ext_vector_type(8)));
typedef float f32x4  __attribute__((ext_vector_type(4)));

__device__ __forceinline__ float4 ld4s(const float* p) { return *reinterpret_cast<const float4*>(p); }
__device__ __forceinline__ void   st4s(float* p, float4 v) { *reinterpret_cast<float4*>(p) = v; }
__device__ __forceinline__ float4 ld4g(const float* __restrict__ p) { return *reinterpret_cast<const float4*>(p); }
__device__ __forceinline__ float fast_sig(float x)  { return 1.f / (1.f + __expf(-x)); }
__device__ __forceinline__ float fast_tanh(float x) { float e = __expf(2.f * x); return 1.f - 2.f / (e + 1.f); }

__device__ __forceinline__ unsigned rne1(float f) {          // f32 -> bf16 bits (RNE)
    unsigned u = __float_as_uint(f);
    return (u + 0x7FFFu + ((u >> 16) & 1u)) >> 16;
}
__device__ __forceinline__ unsigned pk2(float a, float b) {
    return (rne1(a) & 0xFFFFu) | (rne1(b) << 16);
}
__device__ __forceinline__ void st_bf4(short* p, float a, float b, float c, float d) {
    uint2 v; v.x = pk2(a, b); v.y = pk2(c, d);
    *reinterpret_cast<uint2*>(p) = v;
}
__device__ __forceinline__ float bf2f(unsigned hi16) {       // low 16 bits -> float
    return __uint_as_float(hi16 << 16);
}
__device__ __forceinline__ bf16x8 pk8(float4 x0, float4 x1) {
    union { unsigned u[4]; bf16x8 v; } r;
    r.u[0] = pk2(x0.x, x0.y); r.u[1] = pk2(x0.z, x0.w);
    r.u[2] = pk2(x1.x, x1.y); r.u[3] = pk2(x1.z, x1.w);
    return r.v;
}
__device__ __forceinline__ f32x4 mma(bf16x8 a, bf16x8 b, f32x4 c) {
    return __builtin_amdgcn_mfma_f32_16x16x32_bf16(a, b, c, 0, 0, 0);
}
__device__ __forceinline__ f32x4 bias4(const float* __restrict__ p) {
    float4 b = ld4g(p);
    f32x4 r; r[0] = b.x; r[1] = b.y; r[2] = b.z; r[3] = b.w;
    return r;
}

// ---------------- kernel A: Student-t marginal fit ----------------
__global__ __launch_bounds__(256) void fit_kernel(const float* __restrict__ xh,
                                                  float* __restrict__ loc,
                                                  float* __restrict__ scalef) {
    int gid = blockIdx.x * 256 + threadIdx.x;
    int b = gid >> 7, d = gid & 127;
    const float* p = xh + (size_t)b * 192 * 128 + d;
    float s = 0.f;
    for (int t = 0; t < 192; ++t) s += p[t * 128];
    float m = s * (1.0f / 192.0f);
    float v = 0.f;
    for (int t = 0; t < 192; ++t) {
        float c = p[t * 128] - m; c *= c;
        v = (t == 0) ? c : 0.94f * v + (1.0f - 0.94f) * c;
    }
    loc[gid] = m;
    scalef[gid] = fmaxf(sqrtf(v * 0.5f), 1e-5f);
}

// ---------------- kernel B: per-t embedding -> cond[6][32] ----------------
__global__ __launch_bounds__(256) void temb_kernel(
    const float* __restrict__ w1, const float* __restrict__ b1,
    const float* __restrict__ w2, const float* __restrict__ b2,
    const float* __restrict__ wt, const float* __restrict__ bt,
    float* __restrict__ cond_all, FreqArg fq) {
    int t = blockIdx.x;
    int tid = threadIdx.x;
    __shared__ float pe[128], te1[512], te2[512];
    if (tid < 64) {
        double e = (double)t * fq.f[tid];
        pe[tid]      = (float)sin(e);
        pe[tid + 64] = (float)cos(e);
    }
    __syncthreads();
    for (int j = tid; j < 512; j += 256) {
        float acc = b1[j];
        for (int k = 0; k < 128; ++k) acc += pe[k] * w1[k * 512 + j];
        te1[j] = acc / (1.f + expf(-acc));
    }
    __syncthreads();
    for (int j = tid; j < 512; j += 256) {
        float acc = b2[j];
        for (int k = 0; k < 512; ++k) acc += te1[k] * w2[k * 512 + j];
        te2[j] = acc / (1.f + expf(-acc));
    }
    __syncthreads();
    if (tid < 192) {
        int l = tid >> 5, c = tid & 31;
        float acc = bt[l * 32 + c];
        const float* w = wt + (size_t)l * 512 * 32 + c;
        for (int k = 0; k < 512; ++k) acc += te2[k] * w[k * 32];
        cond_all[t * 192 + tid] = acc;
    }
}

// ---------------- kernel P: pack weights as bf16 A-fragments ----------------
// A-frag layout (v_mfma_f32_16x16x32_bf16): lane l elem j holds A[m=l&15][k=(l>>4)*8+j].
// Frags (512 shorts each):
//   0..7    P1:   frag = m2*4+ks        A = w_in[m2*16+m][ks*32+k]
//   8..79   conv: frag = 8+li*12+mg*6+tp*2+gf   A = wdil[li][gf*32+mg*16+m][k][tp]
//   80..103 wout: frag = 80+li*4+mo     A = wout[li][mo*16+m][k]
//   104..105 o1:  frag = 104+m2         A = w_o1[m2*16+m][k] * INV_SQRT_L
//   106..113 o2:  frag = 106+m8         A = w_o2[m8*16+m][k]
__global__ __launch_bounds__(256) void prep_kernel(
    const float* __restrict__ w_in, const float* __restrict__ lyr_wdil,
    const float* __restrict__ lyr_wout, const float* __restrict__ w_o1,
    const float* __restrict__ w_o2, short* __restrict__ wpack) {
    int gid = blockIdx.x * 256 + threadIdx.x;
    if (gid >= 58368) return;
    int j = gid & 7, l = (gid >> 3) & 63, frag = gid >> 9;
    int m = l & 15, k = (l >> 4) * 8 + j;
    float v;
    if (frag < 8) {
        int m2 = frag >> 2, ks = frag & 3;
        v = w_in[(m2 * 16 + m) * 128 + ks * 32 + k];
    } else if (frag < 80) {
        int fi = frag - 8;
        int li = fi / 12, rem = fi % 12;
        int mg = rem / 6, rem2 = rem % 6;
        int tp = rem2 >> 1, gf = rem2 & 1;
        int o = gf * 32 + mg * 16 + m;
        v = lyr_wdil[((li * 64 + o) * 32 + k) * 3 + tp];
    } else if (frag < 104) {
        int fi = frag - 80;
        int li = fi >> 2, mo = fi & 3;
        v = lyr_wout[li * 2048 + (mo * 16 + m) * 32 + k];
    } else if (frag < 106) {
        int m2 = frag - 104;
        v = w_o1[(m2 * 16 + m) * 32 + k] * INV_SQRT_L;
    } else {
        int m8 = frag - 106;
        v = w_o2[(m8 * 16 + m) * 32 + k];
    }
    wpack[gid] = (short)rne1(v);
}

// ---------------- kernel C: 50-step diffusion (MFMA), 2 rows/block ----------------
// col = r*24 + h (48 cols); activations LDS bf16 [col][k], stride 40 shorts (80B).
__global__ __launch_bounds__(512) void diffusion_kernel(
    const float* __restrict__ z_init, const float* __restrict__ noise,
    const float* __restrict__ b_in,  const float* __restrict__ lyr_bdil,
    const float* __restrict__ lyr_bout, const float* __restrict__ b_o1,
    const float* __restrict__ b_o2, const float* __restrict__ cond_all,
    const short* __restrict__ wpack, const float* __restrict__ loc,
    const float* __restrict__ scalef, float* __restrict__ out, SchedArg sc) {

    __shared__ __align__(16) float xsf[48 * 132];   // x state f32 [col][128d], pad 132
    __shared__ __align__(16) short hB [48 * 40];    // h   bf16 [col][32c]
    __shared__ __align__(16) short hcB[49 * 40];    // h+cond, col 48 = zeros
    __shared__ __align__(16) short actB[48 * 40];   // conv act / s
    __shared__ __align__(16) short skB[48 * 40];    // skip accumulator

    const int tid = threadIdx.x;
    const int wv  = __builtin_amdgcn_readfirstlane(tid >> 6);
    const int l   = tid & 63;
    const int ln  = l & 15;          // n within tile / m within A
    const int lq  = l >> 4;          // quarter-wave: C rows lq*4..+3, B k-group lq*8..+7
    const int bb  = blockIdx.x;

    const short* wpP1 = wpack;
    const short* wpCv = wpack + 4096;
    const short* wpWo = wpack + 40960;
    const short* wpO1 = wpack + 53248;
    const short* wpO2 = wpack + 54272;

    // ---- init: z_init [r][128d][24h] -> xsf[col][d]; zero hcB pad col ----
    for (int i = tid; i < 6144; i += 512) {
        int r = i / 3072, rem = i - r * 3072;
        int d = rem / 24, h = rem - d * 24;
        xsf[(r * 24 + h) * 132 + d] = z_init[(size_t)bb * 6144 + i];
    }
    for (int i = tid; i < 40; i += 512) {
        hcB[CZ * 40 + i] = 0;
    }
    __syncthreads();

    for (int step = 0; step < T_STEPS; ++step) {
        const int t = T_STEPS - 1 - step;
        const float* cndt = cond_all + t * 192;

        // ======== P1: h = relu(Win @ x + b_in) -> hB, hcB(layer0) ========
        if (wv < 6) {
            const int m2 = wv / 3, n = wv - 3 * m2;
            const int col = n * 16 + ln;
            f32x4 acc = bias4(b_in + m2 * 16 + lq * 4);
            const short* wa = wpP1 + (m2 * 4) * 512 + l * 8;
            const float* xc = xsf + col * 132 + lq * 8;
#pragma unroll
            for (int ks = 0; ks < 4; ++ks) {
                bf16x8 a = *reinterpret_cast<const bf16x8*>(wa + ks * 512);
                float4 x0 = ld4s(xc + ks * 32);
                float4 x1 = ld4s(xc + ks * 32 + 4);
                acc = mma(a, pk8(x0, x1), acc);
            }
            float4 cv = ld4g(cndt + m2 * 16 + lq * 4);
            float h0 = fmaxf(acc[0], 0.f), h1 = fmaxf(acc[1], 0.f);
            float h2 = fmaxf(acc[2], 0.f), h3 = fmaxf(acc[3], 0.f);
            short* hp = hB + col * 40 + m2 * 16 + lq * 4;
            st_bf4(hp, h0, h1, h2, h3);
            st_bf4(hcB + col * 40 + m2 * 16 + lq * 4,
                   h0 + cv.x, h1 + cv.y, h2 + cv.z, h3 + cv.w);
        } else {
            // waves 6,7: zero the skip accumulator (dead since last o1)
            unsigned* sz = reinterpret_cast<unsigned*>(skB);
            for (int i = tid - 384; i < 960; i += 128) sz[i] = 0u;
        }
        __syncthreads();

        // ======== 6 residual layers ========
        for (int li = 0; li < 6; ++li) {
            const int d = 1 << li;
            // ---- conv (3 shifted K=32 GEMMs) + gated act, in-register pairing ----
            if (wv < 6) {
                const int mg = wv / 3, n = wv - 3 * mg;
                const int col = n * 16 + ln;
                const int r = (col >= 24) ? 1 : 0;
                const int h = col - r * 24;
                f32x4 accg = bias4(lyr_bdil + li * 64 + mg * 16 + lq * 4);
                f32x4 accf = bias4(lyr_bdil + li * 64 + 32 + mg * 16 + lq * 4);
                const short* wc = wpCv + (li * 12 + mg * 6) * 512 + l * 8;
                const int tp0 = (li == 5) ? 1 : 0;
                const int tp1 = (li == 5) ? 1 : 2;
                for (int tp = tp0; tp <= tp1; ++tp) {
                    int hh = h + (tp - 1) * d;
                    int colp = ((unsigned)hh < 24u) ? (r * 24 + hh) : CZ;
                    bf16x8 b = *reinterpret_cast<const bf16x8*>(hcB + colp * 40 + lq * 8);
                    bf16x8 ag = *reinterpret_cast<const bf16x8*>(wc + (tp * 2 + 0) * 512);
                    bf16x8 af = *reinterpret_cast<const bf16x8*>(wc + (tp * 2 + 1) * 512);
                    accg = mma(ag, b, accg);
                    accf = mma(af, b, accf);
                }
                st_bf4(actB + col * 40 + mg * 16 + lq * 4,
                       fast_tanh(accf[0]) * fast_sig(accg[0]),
                       fast_tanh(accf[1]) * fast_sig(accg[1]),
                       fast_tanh(accf[2]) * fast_sig(accg[2]),
                       fast_tanh(accf[3]) * fast_sig(accg[3]));
            }
            __syncthreads();

            // ---- wout: res -> h,hc RMW; sk -> skip RMW (12 tiles) ----
#pragma unroll
            for (int rep = 0; rep < 2; ++rep) {
                int mo, n;
                bool active;
                if (rep == 0) { mo = wv & 3; n = wv >> 2; active = true; }
                else          { mo = wv;    n = 2;       active = (wv < 4); }
                if (active) {
                    const int col = n * 16 + ln;
                    bf16x8 a = *reinterpret_cast<const bf16x8*>(wpWo + (li * 4 + mo) * 512 + l * 8);
                    bf16x8 b = *reinterpret_cast<const bf16x8*>(actB + col * 40 + lq * 8);
                    f32x4 acc = bias4(lyr_bout + li * 64 + mo * 16 + lq * 4);
                    acc = mma(a, b, acc);
                    if (mo < 2) {
                        short* hp = hB + col * 40 + mo * 16 + lq * 4;
                        uint2 hv = *reinterpret_cast<uint2*>(hp);
                        float n0 = (bf2f(hv.x & 0xFFFFu)  + acc[0]) * RS2;
                        float n1 = (bf2f(hv.x >> 16)      + acc[1]) * RS2;
                        float n2 = (bf2f(hv.y & 0xFFFFu)  + acc[2]) * RS2;
                        float n3 = (bf2f(hv.y >> 16)      + acc[3]) * RS2;
                        st_bf4(hp, n0, n1, n2, n3);
                        if (li < 5) {
                            float4 cv = ld4g(cndt + (li + 1) * 32 + mo * 16 + lq * 4);
                            st_bf4(hcB + col * 40 + mo * 16 + lq * 4,
                                   n0 + cv.x, n1 + cv.y, n2 + cv.z, n3 + cv.w);
                        }
                    } else {
                        short* sp = skB + col * 40 + (mo - 2) * 16 + lq * 4;
                        uint2 sv = *reinterpret_cast<uint2*>(sp);
                        st_bf4(sp,
                               bf2f(sv.x & 0xFFFFu) + acc[0],
                               bf2f(sv.x >> 16)     + acc[1],
                               bf2f(sv.y & 0xFFFFu) + acc[2],
                               bf2f(sv.y >> 16)     + acc[3]);
                    }
                }
            }
            __syncthreads();
        }

        // ======== o1: s = relu(b_o1 + Wo1s @ skip) -> actB ========
        if (wv < 6) {
            const int m2 = wv / 3, n = wv - 3 * m2;
            const int col = n * 16 + ln;
            bf16x8 a = *reinterpret_cast<const bf16x8*>(wpO1 + m2 * 512 + l * 8);
            bf16x8 b = *reinterpret_cast<const bf16x8*>(skB + col * 40 + lq * 8);
            f32x4 acc = bias4(b_o1 + m2 * 16 + lq * 4);
            acc = mma(a, b, acc);
            st_bf4(actB + col * 40 + m2 * 16 + lq * 4,
                   fmaxf(acc[0], 0.f), fmaxf(acc[1], 0.f),
                   fmaxf(acc[2], 0.f), fmaxf(acc[3], 0.f));
        }
        __syncthreads();

        // ======== o2: eps = b_o2 + Wo2 @ s; fused DDPM x-update ========
        {
            const float cx0 = sc.cx0[t], cxt = sc.cxt[t], sig = sc.sig[t];
            const float s1m = sc.s1m[t], isab = sc.isab[t];
            const float* nzb = noise + ((size_t)step * NB + bb * 2) * 3072;
            bf16x8 a = *reinterpret_cast<const bf16x8*>(wpO2 + wv * 512 + l * 8);
            const int d0 = wv * 16 + lq * 4;
#pragma unroll
            for (int n = 0; n < 3; ++n) {
                const int col = n * 16 + ln;
                const int r = (col >= 24) ? 1 : 0;
                const int h = col - r * 24;
                bf16x8 b = *reinterpret_cast<const bf16x8*>(actB + col * 40 + lq * 8);
                f32x4 acc = bias4(b_o2 + d0);
                acc = mma(a, b, acc);
                float* xp = xsf + col * 132 + d0;
                float4 xv = ld4s(xp);
                const float* nzp = nzb + r * 3072 + h;
                float4 rr;
#pragma unroll
                for (int i = 0; i < 4; ++i) {
                    float xvv = (&xv.x)[i];
                    float nz = nzp[(d0 + i) * 24];
                    float x0 = fminf(fmaxf((xvv - s1m * acc[i]) * isab, -1.f), 1.f);
                    (&rr.x)[i] = cx0 * x0 + cxt * xvv + sig * nz;
                }
                st4s(xp, rr);
            }
        }
        __syncthreads();
    }

    // ---- epilogue: Gaussian -> Student-t4, coalesced writes ----
    {
        const int b = (bb * 2) & 31;   // rows bb*2, bb*2+1 -> b, b+1 (same s)
        for (int i = tid; i < 1536; i += 512) {
            int col = i >> 5, q = i & 31;
            int r = (col >= 24) ? 1 : 0;
            int h = col - r * 24;
            float4 zv = ld4s(xsf + col * 132 + q * 4);
            float4 l4 = ld4g(loc + (b + r) * 128 + q * 4);
            float4 s4 = ld4g(scalef + (b + r) * 128 + q * 4);
            float4 o4;
#pragma unroll
            for (int e = 0; e < 4; ++e) {
                float u = 0.5f * (1.f + erff((&zv.x)[e] * RS2));
                u = fminf(fmaxf(u, 1e-6f), 1.f - 1e-6f);
                float a4 = fminf(fmaxf(4.f * u * (1.f - u), 1e-12f), 1.f);
                float rr = sqrtf(a4);
                float q2 = 2.f * sqrtf(fmaxf(cosf(acosf(rr) * (1.f / 3.f)) / rr - 1.f, 0.f));
                float tstd = (u < 0.5f) ? -q2 : q2;
                (&o4.x)[e] = (&l4.x)[e] + (&s4.x)[e] * tstd;
            }
            *reinterpret_cast<float4*>(out + ((size_t)(bb * 2 + r) * 24 + h) * 128 + q * 4) = o4;
        }
    }
}

// ---------------- host ----------------
extern "C" void kernel_launch(void* const* d_in, const int* in_sizes, int n_in,
                              void* d_out, int out_size, void* d_ws, size_t ws_size,
                              hipStream_t stream) {
    const float* x_hist  = (const float*)d_in[0];
    const float* z_init  = (const float*)d_in[1];
    const float* noise   = (const float*)d_in[2];
    const float* w_in    = (const float*)d_in[3];
    const float* b_in    = (const float*)d_in[4];
    const float* temb_w1 = (const float*)d_in[5];
    const float* temb_b1 = (const float*)d_in[6];
    const float* temb_w2 = (const float*)d_in[7];
    const float* temb_b2 = (const float*)d_in[8];
    const float* lyr_wt  = (const float*)d_in[9];
    const float* lyr_bt  = (const float*)d_in[10];
    const float* lyr_wdil= (const float*)d_in[11];
    const float* lyr_bdil= (const float*)d_in[12];
    const float* lyr_wout= (const float*)d_in[13];
    const float* lyr_bout= (const float*)d_in[14];
    const float* w_o1    = (const float*)d_in[15];
    const float* b_o1    = (const float*)d_in[16];
    const float* w_o2    = (const float*)d_in[17];
    const float* b_o2    = (const float*)d_in[18];
    float* out = (float*)d_out;

    float* loc      = (float*)d_ws;                     // 4096 f32
    float* scalef   = loc + 4096;                       // 4096 f32
    float* cond_all = scalef + 4096;                    // 9600 f32
    short* wpack    = (short*)d_ws + WPACK_SHORT_OFF;   // 58368 bf16

    SchedArg sa;
    double abar = 1.0;
    for (int t = 0; t < T_STEPS; ++t) {
        double beta  = 1e-4 + (0.1 - 1e-4) * ((double)t / 49.0);
        double alpha = 1.0 - beta;
        double abprev = abar;
        abar *= alpha;
        sa.cx0[t]  = (float)(beta * sqrt(abprev) / (1.0 - abar));
        sa.cxt[t]  = (float)((1.0 - abprev) * sqrt(alpha) / (1.0 - abar));
        double pv  = beta * (1.0 - abprev) / (1.0 - abar);
        sa.sig[t]  = (t > 0) ? (float)sqrt(pv) : 0.f;
        sa.s1m[t]  = (float)sqrt(1.0 - abar);
        sa.isab[t] = (float)(1.0 / sqrt(abar));
    }
    FreqArg fa;
    for (int j = 0; j < 64; ++j) fa.f[j] = pow(10.0, (double)j * 4.0 / 63.0);

    prep_kernel<<<228, 256, 0, stream>>>(w_in, lyr_wdil, lyr_wout, w_o1, w_o2, wpack);
    fit_kernel<<<16, 256, 0, stream>>>(x_hist, loc, scalef);
    temb_kernel<<<T_STEPS, 256, 0, stream>>>(temb_w1, temb_b1, temb_w2, temb_b2,
                                             lyr_wt, lyr_bt, cond_all, fa);
    diffusion_kernel<<<256, 512, 0, stream>>>(z_init, noise, b_in, lyr_bdil,
                                              lyr_bout, b_o1, b_o2, cond_all,
                                              wpack, loc, scalef, out, sa);
}